// Round 10
// baseline (310.866 us; speedup 1.0000x reference)
//
#include <hip/hip_runtime.h>
#include <hip/hip_bf16.h>
#include <math.h>

#define NB 16
#define NS 4096
#define ND 1024
#define NM (NB * NS)

// workspace layout (float offsets)
#define WS_T       0                            // 16*1024
#define WS_SCORES  16384                        // 16*4096 (fallback path)
#define WS_WEIGHTS (WS_SCORES + NB * NS)        // 16*4096
#define WS_SHARED  (WS_WEIGHTS + NB * NS)       // 2MB: wbf16 (convw->scores); fallback: part overlay
#define WS_XBF16   (WS_SHARED + 524288)         // 67.1M ushorts (134 MB)
#define WS_SPART   (WS_XBF16 + 33554432)        // 2MB: spart (scores->softmax) then part (wsum->reduce)
#define WS_NEED    (((size_t)WS_SPART + 524288) * 4)

typedef short v8s __attribute__((ext_vector_type(8)));
typedef float v4f __attribute__((ext_vector_type(4)));
typedef unsigned short ushort;

#define G_AS __attribute__((address_space(1)))
#define L_AS __attribute__((address_space(3)))

__device__ __forceinline__ ushort f2bf(float f) {
    __hip_bfloat16 h = __float2bfloat16(f);
    return *reinterpret_cast<ushort*>(&h);
}

__device__ __forceinline__ float bf2f(ushort u) {
    return __uint_as_float(((unsigned)u) << 16);
}

__device__ __forceinline__ float fast_tanh(float x) {
    float e = __expf(2.0f * x);
    return 1.0f - 2.0f / (e + 1.0f);
}

// ---------------- kernel 0a: W_in fp32 -> bf16 ----------------
__global__ __launch_bounds__(256) void convw_kernel(const float* __restrict__ W,
                                                    ushort* __restrict__ Wb) {
    int flat = blockIdx.x * 256 + threadIdx.x;
#pragma unroll
    for (int j = 0; j < 2; ++j) {
        int idx = flat + j * 131072;
        float4 v = ((const float4*)W)[idx];
        ushort4 o;
        o.x = f2bf(v.x); o.y = f2bf(v.y); o.z = f2bf(v.z); o.w = f2bf(v.w);
        ((ushort4*)Wb)[idx] = o;
    }
}

// ---------------- kernel 0b: x fp32 -> bf16 (fast path only) ----------------
__global__ __launch_bounds__(256) void convx_kernel(const float* __restrict__ x,
                                                    ushort* __restrict__ xb) {
    size_t base = (size_t)blockIdx.x * 256 + threadIdx.x;   // grid 2048
#pragma unroll
    for (int i = 0; i < 16; ++i) {
        size_t idx8 = base + (size_t)i * 524288;
        float4 a = ((const float4*)x)[idx8 * 2];
        float4 c = ((const float4*)x)[idx8 * 2 + 1];
        v8s o;
        o[0] = (short)f2bf(a.x); o[1] = (short)f2bf(a.y);
        o[2] = (short)f2bf(a.z); o[3] = (short)f2bf(a.w);
        o[4] = (short)f2bf(c.x); o[5] = (short)f2bf(c.y);
        o[6] = (short)f2bf(c.z); o[7] = (short)f2bf(c.w);
        ((v8s*)xb)[idx8] = o;
    }
}

// ---------------- kernel 1: t[b][e] = b_in[e]+b_ctx[e]+context[b].W_ctx[e] ----------------
__global__ __launch_bounds__(256) void tvec_kernel(const float* __restrict__ context,
                                                   const float* __restrict__ W_ctx,
                                                   const float* __restrict__ b_in,
                                                   const float* __restrict__ b_ctx,
                                                   float* __restrict__ t) {
    __shared__ float ctx[ND];
    int b = blockIdx.y;
    int tid = threadIdx.x;
    for (int i = tid; i < ND; i += 256) ctx[i] = context[b * ND + i];
    __syncthreads();
    int e = blockIdx.x * 64 + (tid >> 2);
    int kq = tid & 3;
    const float4* wr = (const float4*)(W_ctx + (size_t)e * ND + kq * 256);
    const float4* cr = (const float4*)(ctx + kq * 256);
    float acc = 0.f;
#pragma unroll 4
    for (int k = 0; k < 64; ++k) {
        float4 w = wr[k];
        float4 c = cr[k];
        acc += c.x * w.x + c.y * w.y + c.z * w.z + c.w * w.w;
    }
    acc += __shfl_xor(acc, 1);
    acc += __shfl_xor(acc, 2);
    if (kq == 0) t[b * ND + e] = acc + b_in[e] + b_ctx[e];
}

// ================= FAST scores: 256x256 tile, BK=64, m201-style 4-phase/K-tile =================
// 512 thr / 8 waves (2M x 4N), per-wave 128x64, acc[8][4]=128 AGPR. LDS: A,B double-buffered
// per K-tile (32 KB each buf) = 128 KB. Per phase: stage 1 half-tile (2 gload_lds) + 8
// ds_read_b128 -> barrier -> setprio(1) 16 MFMA setprio(0) -> barrier. vmcnt(0) only at
// K-tile boundaries. LDS granule column XOR-swizzled by row&7 (pre-swizzled global source,
// linear LDS dest; same XOR on ds_read) -> 16-way bank conflict becomes 2-way (free).
__global__ __launch_bounds__(512) void scores_tile_kernel(const ushort* __restrict__ xbf,
                                                          const ushort* __restrict__ Wb,
                                                          const float* __restrict__ t,
                                                          const float* __restrict__ w_att,
                                                          float* __restrict__ spart) {
    __shared__ ushort As[2][16384];  // 32 KB per buf: granule (row*8 + swz_col), 8 ushorts each
    __shared__ ushort Bs[2][16384];
    __shared__ float red[8][128];    // per-wave row partials

    int tid = threadIdx.x;
    int o = blockIdx.x;              // 1024 blocks = 8 xcd x (32 rt x 4 ct)
    int xcd = o & 7, idx = o >> 3;
    int ct = idx & 3;
    int rt = xcd * 32 + (idx >> 2);
    int row0 = rt << 8;
    int e0 = ct << 8;
    int b = row0 >> 12;              // 256 | 4096: no block crosses a batch

    // staging: thread handles phys granules g0=tid (row tid>>3) and g1=tid+512 (row 64+(tid>>3))
    // within each half-tile. Global source column pre-swizzled: col = (tid&7) ^ ((tid>>3)&7).
    int scol = ((tid & 7) ^ ((tid >> 3) & 7)) * 8;
    const ushort* gA = xbf + (size_t)(row0 + (tid >> 3)) * ND + scol;
    const ushort* gB = Wb + (size_t)(e0 + (tid >> 3)) * ND + scol;

    int wid = tid >> 6, l = tid & 63;
    int l15 = l & 15, kq4 = l >> 4;
    int l7 = l15 & 7;
    int WM = (wid >> 2) * 128;       // wave M base (2 groups)
    int WN = (wid & 3) * 64;         // wave N base (4 groups)

    v4f acc[8][4];
#pragma unroll
    for (int i = 0; i < 8; ++i)
#pragma unroll
        for (int j = 0; j < 4; ++j) acc[i][j] = (v4f)(0.f);

    // stage half H (rows 128H..128H+127) of A K-tile at k-offset KO into buf SB
#define STAGE_A(SB, H, KO)                                                                              \
    {                                                                                                   \
        __builtin_amdgcn_global_load_lds((const G_AS void*)(gA + (size_t)(H) * 128 * ND + (KO)),        \
                                         (L_AS void*)&As[SB][((H) * 1024 + tid) * 8], 16, 0, 0);        \
        __builtin_amdgcn_global_load_lds((const G_AS void*)(gA + (size_t)((H) * 128 + 64) * ND + (KO)), \
                                         (L_AS void*)&As[SB][((H) * 1024 + 512 + tid) * 8], 16, 0, 0);  \
    }
#define STAGE_B(SB, H, KO)                                                                              \
    {                                                                                                   \
        __builtin_amdgcn_global_load_lds((const G_AS void*)(gB + (size_t)(H) * 128 * ND + (KO)),        \
                                         (L_AS void*)&Bs[SB][((H) * 1024 + tid) * 8], 16, 0, 0);        \
        __builtin_amdgcn_global_load_lds((const G_AS void*)(gB + (size_t)((H) * 128 + 64) * ND + (KO)), \
                                         (L_AS void*)&Bs[SB][((H) * 1024 + 512 + tid) * 8], 16, 0, 0);  \
    }

#define PHASE(BUF, KK, MH, STMT)                                                                   \
    {                                                                                              \
        STMT;                                                                                      \
        const int kswz = (((KK) * 4 + kq4) ^ l7) * 8;                                              \
        v8s af[4], bf[4];                                                                          \
        _Pragma("unroll") for (int j = 0; j < 4; ++j)                                              \
            af[j] = *(const v8s*)&As[BUF][(WM + ((MH) * 4 + j) * 16 + l15) * 64 + kswz];           \
        _Pragma("unroll") for (int n = 0; n < 4; ++n)                                              \
            bf[n] = *(const v8s*)&Bs[BUF][(WN + n * 16 + l15) * 64 + kswz];                        \
        __builtin_amdgcn_s_barrier();                                                              \
        __builtin_amdgcn_s_setprio(1);                                                             \
        _Pragma("unroll") for (int j = 0; j < 4; ++j)                                              \
            _Pragma("unroll") for (int n = 0; n < 4; ++n)                                          \
                acc[(MH) * 4 + j][n] = __builtin_amdgcn_mfma_f32_16x16x32_bf16(                    \
                    af[j], bf[n], acc[(MH) * 4 + j][n], 0, 0, 0);                                  \
        __builtin_amdgcn_s_setprio(0);                                                             \
        __builtin_amdgcn_s_barrier();                                                              \
    }

    // compute K-tile in BUF; stage next K-tile (k-offset KON) into SB across the 4 phases
#define KTILE(BUF, SB, KON, DOST)                                  \
    PHASE(BUF, 0, 0, if (DOST) STAGE_A(SB, 0, KON));               \
    PHASE(BUF, 0, 1, if (DOST) STAGE_A(SB, 1, KON));               \
    PHASE(BUF, 1, 0, if (DOST) STAGE_B(SB, 0, KON));               \
    PHASE(BUF, 1, 1, if (DOST) STAGE_B(SB, 1, KON));               \
    asm volatile("s_waitcnt vmcnt(0)" ::: "memory");               \
    __builtin_amdgcn_s_barrier();

    // prologue: K-tile 0 into buf0
    STAGE_A(0, 0, 0);
    STAGE_A(0, 1, 0);
    STAGE_B(0, 0, 0);
    STAGE_B(0, 1, 0);
    asm volatile("s_waitcnt vmcnt(0)" ::: "memory");
    __builtin_amdgcn_s_barrier();

#pragma unroll 1
    for (int it = 0; it < 8; ++it) {
        int kbase = it * 128;
        KTILE(0, 1, kbase + 64, true);            // compute even K-tile, stage odd into buf1
        KTILE(1, 0, kbase + 128, (it < 7));       // compute odd K-tile, stage next even into buf0
    }

#undef KTILE
#undef PHASE
#undef STAGE_B
#undef STAGE_A

    // ---- fused epilogue: tanh + dot(w_att) over this wave's 64 e-cols ----
    float s[8][4];
#pragma unroll
    for (int i = 0; i < 8; ++i)
#pragma unroll
        for (int j = 0; j < 4; ++j) s[i][j] = 0.f;

#pragma unroll
    for (int nf = 0; nf < 4; ++nf) {
        int e = e0 + WN + nf * 16 + l15;
        float tv = t[b * ND + e];
        float wv = w_att[e];
#pragma unroll
        for (int mf = 0; mf < 8; ++mf)
#pragma unroll
            for (int r = 0; r < 4; ++r)
                s[mf][r] += fast_tanh(acc[mf][nf][r] + tv) * wv;
    }
#pragma unroll
    for (int mf = 0; mf < 8; ++mf)
#pragma unroll
        for (int r = 0; r < 4; ++r) {
            float v = s[mf][r];
            v += __shfl_xor(v, 1);
            v += __shfl_xor(v, 2);
            v += __shfl_xor(v, 4);
            v += __shfl_xor(v, 8);
            s[mf][r] = v;
        }
    if (l15 == 0) {
#pragma unroll
        for (int mf = 0; mf < 8; ++mf)
#pragma unroll
            for (int r = 0; r < 4; ++r)
                red[wid][mf * 16 + kq4 * 4 + r] = s[mf][r];
    }
    __syncthreads();
    // combine the 4 N-waves of each M-group: waves mg*4 + {0..3}
    if (tid < 256) {
        int mg = tid >> 7;
        int rl = tid & 127;
        float v = red[mg * 4 + 0][rl] + red[mg * 4 + 1][rl] +
                  red[mg * 4 + 2][rl] + red[mg * 4 + 3][rl];
        spart[ct * 65536 + row0 + mg * 128 + rl] = v;
    }
}

// ================= FALLBACK scores (round-3 verbatim, proven) =================
__global__ __launch_bounds__(512) void scores_mfma_kernel(const float* __restrict__ x,
                                                          const ushort* __restrict__ Wb,
                                                          const float* __restrict__ t,
                                                          const float* __restrict__ w_att,
                                                          float* __restrict__ scores) {
    __shared__ ushort As[2][64 * 256];
    __shared__ float red[8][64];

    int tid = threadIdx.x;
    int row0 = blockIdx.x * 64;
    int b = row0 >> 12;
    const float4* xf4 = (const float4*)x;

    int sr = tid >> 3;
    int sc = tid & 7;
    int swzbase = (sr & 7) << 3;

    float4 nx[8];
#pragma unroll
    for (int j = 0; j < 8; ++j)
        nx[j] = xf4[(size_t)(row0 + sr) * 256 + sc + j * 8];
#pragma unroll
    for (int j = 0; j < 8; ++j) {
        int c4 = sc + j * 8;
        ushort4 o;
        o.x = f2bf(nx[j].x); o.y = f2bf(nx[j].y); o.z = f2bf(nx[j].z); o.w = f2bf(nx[j].w);
        *(ushort4*)&As[0][sr * 256 + ((c4 * 4) ^ swzbase)] = o;
    }
    __syncthreads();

    int w = tid >> 6;
    int l = tid & 63;
    int l15 = l & 15;
    int kofs = (l >> 4) * 8;
    int xorv = (l & 7) << 3;
    int n0 = w * 128;

    v4f acc[2][4][4];
#pragma unroll
    for (int p = 0; p < 2; ++p)
#pragma unroll
        for (int i = 0; i < 4; ++i)
#pragma unroll
            for (int j = 0; j < 4; ++j) acc[p][i][j] = (v4f)(0.f);

    const ushort* bbase0 = Wb + (size_t)(n0 + l15) * ND + kofs;
    const ushort* bbase1 = bbase0 + (size_t)64 * ND;

#pragma unroll
    for (int kh = 0; kh < 4; ++kh) {
        if (kh < 3) {
#pragma unroll
            for (int j = 0; j < 8; ++j)
                nx[j] = xf4[(size_t)(row0 + sr) * 256 + (kh + 1) * 64 + sc + j * 8];
        }
        const ushort* Ab = &As[kh & 1][0];
        int kb = kh * 256;

        v8s b0c[4], b0n[4], b1[4];
#pragma unroll
        for (int nf = 0; nf < 4; ++nf) b0c[nf] = *(const v8s*)(bbase0 + (size_t)nf * 16 * ND + kb);

#pragma unroll
        for (int ks = 0; ks < 8; ++ks) {
            int kk = kb + ks * 32;
            int elem = (ks * 32 + kofs) ^ xorv;
            v8s af[4];
#pragma unroll
            for (int mf = 0; mf < 4; ++mf)
                af[mf] = *(const v8s*)&Ab[(mf * 16 + l15) * 256 + elem];
#pragma unroll
            for (int nf = 0; nf < 4; ++nf)
                b1[nf] = *(const v8s*)(bbase1 + (size_t)nf * 16 * ND + kk);
            if (ks < 7) {
#pragma unroll
                for (int nf = 0; nf < 4; ++nf)
                    b0n[nf] = *(const v8s*)(bbase0 + (size_t)nf * 16 * ND + kk + 32);
            }
#pragma unroll
            for (int mf = 0; mf < 4; ++mf)
#pragma unroll
                for (int nf = 0; nf < 4; ++nf)
                    acc[0][mf][nf] = __builtin_amdgcn_mfma_f32_16x16x32_bf16(
                        af[mf], b0c[nf], acc[0][mf][nf], 0, 0, 0);
#pragma unroll
            for (int mf = 0; mf < 4; ++mf)
#pragma unroll
                for (int nf = 0; nf < 4; ++nf)
                    acc[1][mf][nf] = __builtin_amdgcn_mfma_f32_16x16x32_bf16(
                        af[mf], b1[nf], acc[1][mf][nf], 0, 0, 0);
#pragma unroll
            for (int nf = 0; nf < 4; ++nf) b0c[nf] = b0n[nf];
        }

        if (kh < 3) {
#pragma unroll
            for (int j = 0; j < 8; ++j) {
                int c4 = sc + j * 8;
                ushort4 o;
                o.x = f2bf(nx[j].x); o.y = f2bf(nx[j].y); o.z = f2bf(nx[j].z); o.w = f2bf(nx[j].w);
                *(ushort4*)&As[(kh + 1) & 1][sr * 256 + ((c4 * 4) ^ swzbase)] = o;
            }
            __syncthreads();
        }
    }

    float s[4][4];
#pragma unroll
    for (int i = 0; i < 4; ++i)
#pragma unroll
        for (int j = 0; j < 4; ++j) s[i][j] = 0.f;

#pragma unroll
    for (int pass = 0; pass < 2; ++pass)
#pragma unroll
        for (int nf = 0; nf < 4; ++nf) {
            int e = n0 + pass * 64 + nf * 16 + l15;
            float tv = t[b * ND + e];
            float wv = w_att[e];
#pragma unroll
            for (int mf = 0; mf < 4; ++mf)
#pragma unroll
                for (int r = 0; r < 4; ++r)
                    s[mf][r] += fast_tanh(acc[pass][mf][nf][r] + tv) * wv;
        }

#pragma unroll
    for (int mf = 0; mf < 4; ++mf)
#pragma unroll
        for (int r = 0; r < 4; ++r) {
            float v = s[mf][r];
            v += __shfl_xor(v, 1);
            v += __shfl_xor(v, 2);
            v += __shfl_xor(v, 4);
            v += __shfl_xor(v, 8);
            s[mf][r] = v;
        }
    if (l15 == 0) {
#pragma unroll
        for (int mf = 0; mf < 4; ++mf)
#pragma unroll
            for (int r = 0; r < 4; ++r)
                red[w][mf * 16 + (l >> 4) * 4 + r] = s[mf][r];
    }
    __syncthreads();
    if (tid < 64) {
        float v = 0.f;
#pragma unroll
        for (int ww = 0; ww < 8; ++ww) v += red[ww][tid];
        scores[(size_t)b * NS + (row0 & (NS - 1)) + tid] = v;
    }
}

// ---------------- softmax (fast): sum 4 col-tile partials, then softmax ----------------
__global__ __launch_bounds__(256) void softmax4_kernel(const float* __restrict__ spart,
                                                       float* __restrict__ weights) {
    int b = blockIdx.x;
    int tid = threadIdx.x;
    float v[16];
    float lmax = -1e30f;
#pragma unroll
    for (int i = 0; i < 16; ++i) {
        int grow = b * NS + tid + i * 256;
        float sum = 0.f;
#pragma unroll
        for (int c = 0; c < 4; ++c) sum += spart[c * 65536 + grow];
        v[i] = sum;
        lmax = fmaxf(lmax, sum);
    }
#pragma unroll
    for (int off = 32; off >= 1; off >>= 1) lmax = fmaxf(lmax, __shfl_xor(lmax, off));
    __shared__ float redm[4];
    int wave = tid >> 6;
    if ((tid & 63) == 0) redm[wave] = lmax;
    __syncthreads();
    float bmax = fmaxf(fmaxf(redm[0], redm[1]), fmaxf(redm[2], redm[3]));

    float lsum = 0.f;
#pragma unroll
    for (int i = 0; i < 16; ++i) {
        v[i] = expf(v[i] - bmax);
        lsum += v[i];
    }
#pragma unroll
    for (int off = 32; off >= 1; off >>= 1) lsum += __shfl_xor(lsum, off);
    __shared__ float reds[4];
    if ((tid & 63) == 0) reds[wave] = lsum;
    __syncthreads();
    float inv = 1.0f / (reds[0] + reds[1] + reds[2] + reds[3]);
#pragma unroll
    for (int i = 0; i < 16; ++i) weights[b * NS + tid + i * 256] = v[i] * inv;
}

// ---------------- softmax (fallback): plain ----------------
__global__ __launch_bounds__(256) void softmax_kernel(const float* __restrict__ scores,
                                                      float* __restrict__ weights) {
    int b = blockIdx.x;
    int tid = threadIdx.x;
    float v[16];
    float lmax = -1e30f;
#pragma unroll
    for (int i = 0; i < 16; ++i) {
        v[i] = scores[b * NS + tid + i * 256];
        lmax = fmaxf(lmax, v[i]);
    }
#pragma unroll
    for (int off = 32; off >= 1; off >>= 1) lmax = fmaxf(lmax, __shfl_xor(lmax, off));
    __shared__ float redm[4];
    int wave = tid >> 6;
    if ((tid & 63) == 0) redm[wave] = lmax;
    __syncthreads();
    float bmax = fmaxf(fmaxf(redm[0], redm[1]), fmaxf(redm[2], redm[3]));

    float lsum = 0.f;
#pragma unroll
    for (int i = 0; i < 16; ++i) {
        v[i] = expf(v[i] - bmax);
        lsum += v[i];
    }
#pragma unroll
    for (int off = 32; off >= 1; off >>= 1) lsum += __shfl_xor(lsum, off);
    __shared__ float reds[4];
    if ((tid & 63) == 0) reds[wave] = lsum;
    __syncthreads();
    float inv = 1.0f / (reds[0] + reds[1] + reds[2] + reds[3]);
#pragma unroll
    for (int i = 0; i < 16; ++i) weights[b * NS + tid + i * 256] = v[i] * inv;
}

// ---------------- wsum fp32 (fallback) ----------------
__global__ __launch_bounds__(256) void wsum_kernel(const float* __restrict__ x,
                                                   const float* __restrict__ w,
                                                   float* __restrict__ part) {
    int sc = blockIdx.x, b = blockIdx.y;
    int d0 = threadIdx.x * 4;
    const float* xb = x + ((size_t)b * NS + sc * 128) * ND;
    const float* wb = w + b * NS + sc * 128;
    float4 acc = {0.f, 0.f, 0.f, 0.f};
    for (int ss = 0; ss < 128; ++ss) {
        float wv = wb[ss];
        float4 xv = *(const float4*)&xb[(size_t)ss * ND + d0];
        acc.x += wv * xv.x;
        acc.y += wv * xv.y;
        acc.z += wv * xv.z;
        acc.w += wv * xv.w;
    }
    *(float4*)&part[(size_t)(b * 32 + sc) * ND + d0] = acc;
}

// ---------------- wsum bf16 (fast) ----------------
__global__ __launch_bounds__(256) void wsum_bf_kernel(const ushort* __restrict__ xbf,
                                                      const float* __restrict__ w,
                                                      float* __restrict__ part) {
    int sc = blockIdx.x, b = blockIdx.y;
    int d0 = threadIdx.x * 4;
    const ushort* xb = xbf + ((size_t)b * NS + sc * 128) * ND;
    const float* wb = w + b * NS + sc * 128;
    float4 acc = {0.f, 0.f, 0.f, 0.f};
    for (int ss = 0; ss < 128; ++ss) {
        float wv = wb[ss];
        ushort4 xv = *(const ushort4*)&xb[(size_t)ss * ND + d0];
        acc.x += wv * bf2f(xv.x);
        acc.y += wv * bf2f(xv.y);
        acc.z += wv * bf2f(xv.z);
        acc.w += wv * bf2f(xv.w);
    }
    *(float4*)&part[(size_t)(b * 32 + sc) * ND + d0] = acc;
}

// ---------------- reduce partials -> out ----------------
__global__ __launch_bounds__(256) void reduce_kernel(const float* __restrict__ part,
                                                     float* __restrict__ out) {
    int b = blockIdx.x;
    int d0 = threadIdx.x * 4;
    float4 acc = {0.f, 0.f, 0.f, 0.f};
#pragma unroll
    for (int sc = 0; sc < 32; ++sc) {
        float4 v = *(const float4*)&part[(size_t)(b * 32 + sc) * ND + d0];
        acc.x += v.x;
        acc.y += v.y;
        acc.z += v.z;
        acc.w += v.w;
    }
    *(float4*)&out[b * ND + d0] = acc;
}

extern "C" void kernel_launch(void* const* d_in, const int* in_sizes, int n_in,
                              void* d_out, int out_size, void* d_ws, size_t ws_size,
                              hipStream_t stream) {
    const float* x       = (const float*)d_in[0];
    const float* context = (const float*)d_in[1];
    const float* W_in    = (const float*)d_in[2];
    const float* b_in    = (const float*)d_in[3];
    const float* W_ctx   = (const float*)d_in[4];
    const float* b_ctx   = (const float*)d_in[5];
    const float* w_att   = (const float*)d_in[6];
    // b_att (d_in[7]): softmax is shift-invariant; it cancels.

    float* ws      = (float*)d_ws;
    float* t       = ws + WS_T;
    float* scores  = ws + WS_SCORES;
    float* weights = ws + WS_WEIGHTS;
    ushort* wbf16  = (ushort*)(ws + WS_SHARED);
    ushort* xbf16  = (ushort*)(ws + WS_XBF16);
    float* spart   = ws + WS_SPART;              // fast: spart, then part overlay
    float* partfb  = ws + WS_SHARED;             // fallback: part overlays wbf16
    float* out     = (float*)d_out;

    bool fast = ws_size >= WS_NEED;

    convw_kernel<<<dim3(512), 256, 0, stream>>>(W_in, wbf16);
    tvec_kernel<<<dim3(16, NB), 256, 0, stream>>>(context, W_ctx, b_in, b_ctx, t);
    if (fast) {
        convx_kernel<<<dim3(2048), 256, 0, stream>>>(x, xbf16);
        scores_tile_kernel<<<dim3(1024), 512, 0, stream>>>(xbf16, wbf16, t, w_att, spart);
        softmax4_kernel<<<dim3(NB), 256, 0, stream>>>(spart, weights);
        wsum_bf_kernel<<<dim3(32, NB), 256, 0, stream>>>(xbf16, weights, spart);
        reduce_kernel<<<dim3(NB), 256, 0, stream>>>(spart, out);
    } else {
        scores_mfma_kernel<<<dim3(NM / 64), 512, 0, stream>>>(x, wbf16, t, w_att, scores);
        softmax_kernel<<<dim3(NB), 256, 0, stream>>>(scores, weights);
        wsum_kernel<<<dim3(32, NB), 256, 0, stream>>>(x, weights, partfb);
        reduce_kernel<<<dim3(NB), 256, 0, stream>>>(partfb, out);
    }
}

// Round 11
// 302.169 us; speedup vs baseline: 1.0288x; 1.0288x over previous
//
#include <hip/hip_runtime.h>
#include <hip/hip_bf16.h>
#include <math.h>

#define NB 16
#define NS 4096
#define ND 1024
#define NM (NB * NS)

// workspace layout (float offsets)
#define WS_T       0                            // 16*1024
#define WS_SCORES  16384                        // 16*4096 (fallback path)
#define WS_WEIGHTS (WS_SCORES + NB * NS)        // 16*4096
#define WS_SHARED  (WS_WEIGHTS + NB * NS)       // 2MB: wbf16 (convw->scores); fallback: part overlay
#define WS_XBF16   (WS_SHARED + 524288)         // 67.1M ushorts (134 MB)
#define WS_SPART   (WS_XBF16 + 33554432)        // 2MB: spart (scores->softmax) then part (wsum->reduce)
#define WS_NEED    (((size_t)WS_SPART + 524288) * 4)

typedef short v8s __attribute__((ext_vector_type(8)));
typedef float v4f __attribute__((ext_vector_type(4)));
typedef unsigned short ushort;

#define G_AS __attribute__((address_space(1)))
#define L_AS __attribute__((address_space(3)))

__device__ __forceinline__ ushort f2bf(float f) {
    __hip_bfloat16 h = __float2bfloat16(f);
    return *reinterpret_cast<ushort*>(&h);
}

__device__ __forceinline__ float bf2f(ushort u) {
    return __uint_as_float(((unsigned)u) << 16);
}

__device__ __forceinline__ float fast_tanh(float x) {
    float e = __expf(2.0f * x);
    return 1.0f - 2.0f / (e + 1.0f);
}

// ---------------- kernel 0a: W_in fp32 -> bf16 ----------------
__global__ __launch_bounds__(256) void convw_kernel(const float* __restrict__ W,
                                                    ushort* __restrict__ Wb) {
    int flat = blockIdx.x * 256 + threadIdx.x;
#pragma unroll
    for (int j = 0; j < 2; ++j) {
        int idx = flat + j * 131072;
        float4 v = ((const float4*)W)[idx];
        ushort4 o;
        o.x = f2bf(v.x); o.y = f2bf(v.y); o.z = f2bf(v.z); o.w = f2bf(v.w);
        ((ushort4*)Wb)[idx] = o;
    }
}

// ---------------- kernel 0b: x fp32 -> bf16 (fast path only) ----------------
__global__ __launch_bounds__(256) void convx_kernel(const float* __restrict__ x,
                                                    ushort* __restrict__ xb) {
    size_t base = (size_t)blockIdx.x * 256 + threadIdx.x;   // grid 2048
#pragma unroll
    for (int i = 0; i < 16; ++i) {
        size_t idx8 = base + (size_t)i * 524288;
        float4 a = ((const float4*)x)[idx8 * 2];
        float4 c = ((const float4*)x)[idx8 * 2 + 1];
        v8s o;
        o[0] = (short)f2bf(a.x); o[1] = (short)f2bf(a.y);
        o[2] = (short)f2bf(a.z); o[3] = (short)f2bf(a.w);
        o[4] = (short)f2bf(c.x); o[5] = (short)f2bf(c.y);
        o[6] = (short)f2bf(c.z); o[7] = (short)f2bf(c.w);
        ((v8s*)xb)[idx8] = o;
    }
}

// ---------------- kernel 1: t[b][e] = b_in[e]+b_ctx[e]+context[b].W_ctx[e] ----------------
__global__ __launch_bounds__(256) void tvec_kernel(const float* __restrict__ context,
                                                   const float* __restrict__ W_ctx,
                                                   const float* __restrict__ b_in,
                                                   const float* __restrict__ b_ctx,
                                                   float* __restrict__ t) {
    __shared__ float ctx[ND];
    int b = blockIdx.y;
    int tid = threadIdx.x;
    for (int i = tid; i < ND; i += 256) ctx[i] = context[b * ND + i];
    __syncthreads();
    int e = blockIdx.x * 64 + (tid >> 2);
    int kq = tid & 3;
    const float4* wr = (const float4*)(W_ctx + (size_t)e * ND + kq * 256);
    const float4* cr = (const float4*)(ctx + kq * 256);
    float acc = 0.f;
#pragma unroll 4
    for (int k = 0; k < 64; ++k) {
        float4 w = wr[k];
        float4 c = cr[k];
        acc += c.x * w.x + c.y * w.y + c.z * w.z + c.w * w.w;
    }
    acc += __shfl_xor(acc, 1);
    acc += __shfl_xor(acc, 2);
    if (kq == 0) t[b * ND + e] = acc + b_in[e] + b_ctx[e];
}

// ================= FAST scores: 256x256, BK=64, m201 8-phase + counted vmcnt(8) =================
// 512 thr / 8 waves (2M x 4N), per-wave 128x64, acc[8][4]=128 AGPR. Half-tiles are K-SLICES
// (all 256 rows x K32) so each half is consumed only in 2 of 4 phases -> staging issued 5-6
// phases before use; uniform vmcnt(8) at every even phase (never 0 in main loop).
// LDS granule = s*1024 + row*4 + (kq ^ ((row^(row>>2))&3)); dest-linear staging with
// pre-swizzled global source; reads uniform 2-way (free).
__global__ __launch_bounds__(512) void scores_tile_kernel(const ushort* __restrict__ xbf,
                                                          const ushort* __restrict__ Wb,
                                                          const float* __restrict__ t,
                                                          const float* __restrict__ w_att,
                                                          float* __restrict__ spart) {
    __shared__ ushort As[2][16384];  // 32 KB per buf: 2 K-slices x 1024 granules x 8 ushorts
    __shared__ ushort Bs[2][16384];
    __shared__ float red[8][128];

    int tid = threadIdx.x;
    int o = blockIdx.x;              // 1024 blocks = 8 xcd x (32 rt x 4 ct)
    int xcd = o & 7, idx = o >> 3;
    int ct = idx & 3;
    int rt = xcd * 32 + (idx >> 2);
    int row0 = rt << 8;
    int e0 = ct << 8;
    int b = row0 >> 12;              // 256 | 4096

    // staging: thread handles granules j=tid (row tid>>2) and j=tid+512 (row 128+(tid>>2))
    // of each staged K-slice. Stored kq = (tid&3) ^ g(row); g same for both rows.
    int srow = tid >> 2;
    int sg = (srow ^ (srow >> 2)) & 3;
    int skq = (tid & 3) ^ sg;
    const ushort* gA0 = xbf + (size_t)(row0 + srow) * ND + skq * 8;
    const ushort* gA1 = gA0 + (size_t)128 * ND;
    const ushort* gB0 = Wb + (size_t)(e0 + srow) * ND + skq * 8;
    const ushort* gB1 = gB0 + (size_t)128 * ND;

    int wid = tid >> 6, l = tid & 63;
    int l15 = l & 15, kq4 = l >> 4;
    int kqg = kq4 ^ ((l15 ^ (l15 >> 2)) & 3);   // read-side swizzled k-quarter
    int WM = (wid >> 2) * 128;
    int WN = (wid & 3) * 64;

    v4f acc[8][4];
#pragma unroll
    for (int i = 0; i < 8; ++i)
#pragma unroll
        for (int j = 0; j < 4; ++j) acc[i][j] = (v4f)(0.f);

    // stage K-slice S of tile (k-offset TK ushorts) of matrix MAT into buf BUF
#define STG(MAT, BUF, TK, S)                                                                       \
    {                                                                                              \
        __builtin_amdgcn_global_load_lds((const G_AS void*)(g##MAT##0 + (TK) + (S) * 32),          \
                                         (L_AS void*)&MAT##s[BUF][((S) * 1024 + tid) * 8], 16, 0, 0); \
        __builtin_amdgcn_global_load_lds((const G_AS void*)(g##MAT##1 + (TK) + (S) * 32),          \
                                         (L_AS void*)&MAT##s[BUF][((S) * 1024 + 512 + tid) * 8], 16, 0, 0); \
    }

#define VM8 asm volatile("s_waitcnt vmcnt(8)" ::: "memory")
#define VM4 asm volatile("s_waitcnt vmcnt(4)" ::: "memory")
#define VM0 asm volatile("s_waitcnt vmcnt(0)" ::: "memory")
#define NOSTG
#define NOWAIT

#define PHASE(BUF, KK, MH, STAGE_STMT, WAIT_STMT)                                                  \
    {                                                                                              \
        v8s af[4], bf[4];                                                                          \
        _Pragma("unroll") for (int j = 0; j < 4; ++j)                                              \
            af[j] = *(const v8s*)&As[BUF][((KK) * 1024 +                                           \
                        (WM + ((MH) * 4 + j) * 16 + l15) * 4 + kqg) * 8];                          \
        _Pragma("unroll") for (int n = 0; n < 4; ++n)                                              \
            bf[n] = *(const v8s*)&Bs[BUF][((KK) * 1024 +                                           \
                        (WN + n * 16 + l15) * 4 + kqg) * 8];                                       \
        STAGE_STMT;                                                                                \
        __builtin_amdgcn_s_barrier();                                                              \
        __builtin_amdgcn_s_setprio(1);                                                             \
        _Pragma("unroll") for (int j = 0; j < 4; ++j)                                              \
            _Pragma("unroll") for (int n = 0; n < 4; ++n)                                          \
                acc[(MH) * 4 + j][n] = __builtin_amdgcn_mfma_f32_16x16x32_bf16(                    \
                    af[j], bf[n], acc[(MH) * 4 + j][n], 0, 0, 0);                                  \
        __builtin_amdgcn_s_setprio(0);                                                             \
        WAIT_STMT;                                                                                 \
        __builtin_amdgcn_s_barrier();                                                              \
    }

    // ---- prologue: tile0 (all 4 slices) + tile1 K0 slices; wait tile0 landed ----
    STG(A, 0, 0, 0);
    STG(B, 0, 0, 0);
    STG(A, 0, 0, 1);
    STG(B, 0, 0, 1);
    STG(A, 1, 64, 0);
    STG(B, 1, 64, 0);
    VM4;
    __builtin_amdgcn_s_barrier();

    // ---- main: iters 0..6 compute tiles 2it (buf0), 2it+1 (buf1) ----
#pragma unroll 1
    for (int it = 0; it < 7; ++it) {
        int tk1 = (2 * it + 1) * 64;
        int tk2 = (2 * it + 2) * 64;
        int tk3 = (2 * it + 3) * 64;
        PHASE(0, 0, 0, STG(A, 1, tk1, 1), NOWAIT)
        PHASE(0, 0, 1, STG(B, 1, tk1, 1), VM8)
        PHASE(0, 1, 0, STG(A, 0, tk2, 0), NOWAIT)
        PHASE(0, 1, 1, STG(B, 0, tk2, 0), VM8)
        PHASE(1, 0, 0, STG(A, 0, tk2, 1), NOWAIT)
        PHASE(1, 0, 1, STG(B, 0, tk2, 1), VM8)
        PHASE(1, 1, 0, STG(A, 1, tk3, 0), NOWAIT)
        PHASE(1, 1, 1, STG(B, 1, tk3, 0), VM8)
    }
    // ---- tail iter 7: tiles 14 (buf0), 15 (buf1); drain gradually ----
    PHASE(0, 0, 0, STG(A, 1, 15 * 64, 1), NOWAIT)
    PHASE(0, 0, 1, STG(B, 1, 15 * 64, 1), VM8)
    PHASE(0, 1, 0, NOSTG, NOWAIT)
    PHASE(0, 1, 1, NOSTG, VM4)
    PHASE(1, 0, 0, NOSTG, NOWAIT)
    PHASE(1, 0, 1, NOSTG, VM0)
    PHASE(1, 1, 0, NOSTG, NOWAIT)
    PHASE(1, 1, 1, NOSTG, NOWAIT)

#undef PHASE
#undef NOWAIT
#undef NOSTG
#undef VM0
#undef VM4
#undef VM8
#undef STG

    // ---- fused epilogue: tanh + dot(w_att) over this wave's 64 e-cols ----
    float s[8][4];
#pragma unroll
    for (int i = 0; i < 8; ++i)
#pragma unroll
        for (int j = 0; j < 4; ++j) s[i][j] = 0.f;

#pragma unroll
    for (int nf = 0; nf < 4; ++nf) {
        int e = e0 + WN + nf * 16 + l15;
        float tv = t[b * ND + e];
        float wv = w_att[e];
#pragma unroll
        for (int mf = 0; mf < 8; ++mf)
#pragma unroll
            for (int r = 0; r < 4; ++r)
                s[mf][r] += fast_tanh(acc[mf][nf][r] + tv) * wv;
    }
#pragma unroll
    for (int mf = 0; mf < 8; ++mf)
#pragma unroll
        for (int r = 0; r < 4; ++r) {
            float v = s[mf][r];
            v += __shfl_xor(v, 1);
            v += __shfl_xor(v, 2);
            v += __shfl_xor(v, 4);
            v += __shfl_xor(v, 8);
            s[mf][r] = v;
        }
    if (l15 == 0) {
#pragma unroll
        for (int mf = 0; mf < 8; ++mf)
#pragma unroll
            for (int r = 0; r < 4; ++r)
                red[wid][mf * 16 + kq4 * 4 + r] = s[mf][r];
    }
    __syncthreads();
    if (tid < 256) {
        int mg = tid >> 7;
        int rl = tid & 127;
        float v = red[mg * 4 + 0][rl] + red[mg * 4 + 1][rl] +
                  red[mg * 4 + 2][rl] + red[mg * 4 + 3][rl];
        spart[ct * 65536 + row0 + mg * 128 + rl] = v;
    }
}

// ================= FALLBACK scores (round-3 verbatim, proven) =================
__global__ __launch_bounds__(512) void scores_mfma_kernel(const float* __restrict__ x,
                                                          const ushort* __restrict__ Wb,
                                                          const float* __restrict__ t,
                                                          const float* __restrict__ w_att,
                                                          float* __restrict__ scores) {
    __shared__ ushort As[2][64 * 256];
    __shared__ float red[8][64];

    int tid = threadIdx.x;
    int row0 = blockIdx.x * 64;
    int b = row0 >> 12;
    const float4* xf4 = (const float4*)x;

    int sr = tid >> 3;
    int sc = tid & 7;
    int swzbase = (sr & 7) << 3;

    float4 nx[8];
#pragma unroll
    for (int j = 0; j < 8; ++j)
        nx[j] = xf4[(size_t)(row0 + sr) * 256 + sc + j * 8];
#pragma unroll
    for (int j = 0; j < 8; ++j) {
        int c4 = sc + j * 8;
        ushort4 o;
        o.x = f2bf(nx[j].x); o.y = f2bf(nx[j].y); o.z = f2bf(nx[j].z); o.w = f2bf(nx[j].w);
        *(ushort4*)&As[0][sr * 256 + ((c4 * 4) ^ swzbase)] = o;
    }
    __syncthreads();

    int w = tid >> 6;
    int l = tid & 63;
    int l15 = l & 15;
    int kofs = (l >> 4) * 8;
    int xorv = (l & 7) << 3;
    int n0 = w * 128;

    v4f acc[2][4][4];
#pragma unroll
    for (int p = 0; p < 2; ++p)
#pragma unroll
        for (int i = 0; i < 4; ++i)
#pragma unroll
            for (int j = 0; j < 4; ++j) acc[p][i][j] = (v4f)(0.f);

    const ushort* bbase0 = Wb + (size_t)(n0 + l15) * ND + kofs;
    const ushort* bbase1 = bbase0 + (size_t)64 * ND;

#pragma unroll
    for (int kh = 0; kh < 4; ++kh) {
        if (kh < 3) {
#pragma unroll
            for (int j = 0; j < 8; ++j)
                nx[j] = xf4[(size_t)(row0 + sr) * 256 + (kh + 1) * 64 + sc + j * 8];
        }
        const ushort* Ab = &As[kh & 1][0];
        int kb = kh * 256;

        v8s b0c[4], b0n[4], b1[4];
#pragma unroll
        for (int nf = 0; nf < 4; ++nf) b0c[nf] = *(const v8s*)(bbase0 + (size_t)nf * 16 * ND + kb);

#pragma unroll
        for (int ks = 0; ks < 8; ++ks) {
            int kk = kb + ks * 32;
            int elem = (ks * 32 + kofs) ^ xorv;
            v8s af[4];
#pragma unroll
            for (int mf = 0; mf < 4; ++mf)
                af[mf] = *(const v8s*)&Ab[(mf * 16 + l15) * 256 + elem];
#pragma unroll
            for (int nf = 0; nf < 4; ++nf)
                b1[nf] = *(const v8s*)(bbase1 + (size_t)nf * 16 * ND + kk);
            if (ks < 7) {
#pragma unroll
                for (int nf = 0; nf < 4; ++nf)
                    b0n[nf] = *(const v8s*)(bbase0 + (size_t)nf * 16 * ND + kk + 32);
            }
#pragma unroll
            for (int mf = 0; mf < 4; ++mf)
#pragma unroll
                for (int nf = 0; nf < 4; ++nf)
                    acc[0][mf][nf] = __builtin_amdgcn_mfma_f32_16x16x32_bf16(
                        af[mf], b0c[nf], acc[0][mf][nf], 0, 0, 0);
#pragma unroll
            for (int mf = 0; mf < 4; ++mf)
#pragma unroll
                for (int nf = 0; nf < 4; ++nf)
                    acc[1][mf][nf] = __builtin_amdgcn_mfma_f32_16x16x32_bf16(
                        af[mf], b1[nf], acc[1][mf][nf], 0, 0, 0);
#pragma unroll
            for (int nf = 0; nf < 4; ++nf) b0c[nf] = b0n[nf];
        }

        if (kh < 3) {
#pragma unroll
            for (int j = 0; j < 8; ++j) {
                int c4 = sc + j * 8;
                ushort4 o;
                o.x = f2bf(nx[j].x); o.y = f2bf(nx[j].y); o.z = f2bf(nx[j].z); o.w = f2bf(nx[j].w);
                *(ushort4*)&As[(kh + 1) & 1][sr * 256 + ((c4 * 4) ^ swzbase)] = o;
            }
            __syncthreads();
        }
    }

    float s[4][4];
#pragma unroll
    for (int i = 0; i < 4; ++i)
#pragma unroll
        for (int j = 0; j < 4; ++j) s[i][j] = 0.f;

#pragma unroll
    for (int pass = 0; pass < 2; ++pass)
#pragma unroll
        for (int nf = 0; nf < 4; ++nf) {
            int e = n0 + pass * 64 + nf * 16 + l15;
            float tv = t[b * ND + e];
            float wv = w_att[e];
#pragma unroll
            for (int mf = 0; mf < 4; ++mf)
#pragma unroll
                for (int r = 0; r < 4; ++r)
                    s[mf][r] += fast_tanh(acc[pass][mf][nf][r] + tv) * wv;
        }

#pragma unroll
    for (int mf = 0; mf < 4; ++mf)
#pragma unroll
        for (int r = 0; r < 4; ++r) {
            float v = s[mf][r];
            v += __shfl_xor(v, 1);
            v += __shfl_xor(v, 2);
            v += __shfl_xor(v, 4);
            v += __shfl_xor(v, 8);
            s[mf][r] = v;
        }
    if (l15 == 0) {
#pragma unroll
        for (int mf = 0; mf < 4; ++mf)
#pragma unroll
            for (int r = 0; r < 4; ++r)
                red[w][mf * 16 + (l >> 4) * 4 + r] = s[mf][r];
    }
    __syncthreads();
    if (tid < 64) {
        float v = 0.f;
#pragma unroll
        for (int ww = 0; ww < 8; ++ww) v += red[ww][tid];
        scores[(size_t)b * NS + (row0 & (NS - 1)) + tid] = v;
    }
}

// ---------------- softmax (fast): sum 4 col-tile partials, then softmax ----------------
__global__ __launch_bounds__(256) void softmax4_kernel(const float* __restrict__ spart,
                                                       float* __restrict__ weights) {
    int b = blockIdx.x;
    int tid = threadIdx.x;
    float v[16];
    float lmax = -1e30f;
#pragma unroll
    for (int i = 0; i < 16; ++i) {
        int grow = b * NS + tid + i * 256;
        float sum = 0.f;
#pragma unroll
        for (int c = 0; c < 4; ++c) sum += spart[c * 65536 + grow];
        v[i] = sum;
        lmax = fmaxf(lmax, sum);
    }
#pragma unroll
    for (int off = 32; off >= 1; off >>= 1) lmax = fmaxf(lmax, __shfl_xor(lmax, off));
    __shared__ float redm[4];
    int wave = tid >> 6;
    if ((tid & 63) == 0) redm[wave] = lmax;
    __syncthreads();
    float bmax = fmaxf(fmaxf(redm[0], redm[1]), fmaxf(redm[2], redm[3]));

    float lsum = 0.f;
#pragma unroll
    for (int i = 0; i < 16; ++i) {
        v[i] = expf(v[i] - bmax);
        lsum += v[i];
    }
#pragma unroll
    for (int off = 32; off >= 1; off >>= 1) lsum += __shfl_xor(lsum, off);
    __shared__ float reds[4];
    if ((tid & 63) == 0) reds[wave] = lsum;
    __syncthreads();
    float inv = 1.0f / (reds[0] + reds[1] + reds[2] + reds[3]);
#pragma unroll
    for (int i = 0; i < 16; ++i) weights[b * NS + tid + i * 256] = v[i] * inv;
}

// ---------------- softmax (fallback): plain ----------------
__global__ __launch_bounds__(256) void softmax_kernel(const float* __restrict__ scores,
                                                      float* __restrict__ weights) {
    int b = blockIdx.x;
    int tid = threadIdx.x;
    float v[16];
    float lmax = -1e30f;
#pragma unroll
    for (int i = 0; i < 16; ++i) {
        v[i] = scores[b * NS + tid + i * 256];
        lmax = fmaxf(lmax, v[i]);
    }
#pragma unroll
    for (int off = 32; off >= 1; off >>= 1) lmax = fmaxf(lmax, __shfl_xor(lmax, off));
    __shared__ float redm[4];
    int wave = tid >> 6;
    if ((tid & 63) == 0) redm[wave] = lmax;
    __syncthreads();
    float bmax = fmaxf(fmaxf(redm[0], redm[1]), fmaxf(redm[2], redm[3]));

    float lsum = 0.f;
#pragma unroll
    for (int i = 0; i < 16; ++i) {
        v[i] = expf(v[i] - bmax);
        lsum += v[i];
    }
#pragma unroll
    for (int off = 32; off >= 1; off >>= 1) lsum += __shfl_xor(lsum, off);
    __shared__ float reds[4];
    if ((tid & 63) == 0) reds[wave] = lsum;
    __syncthreads();
    float inv = 1.0f / (reds[0] + reds[1] + reds[2] + reds[3]);
#pragma unroll
    for (int i = 0; i < 16; ++i) weights[b * NS + tid + i * 256] = v[i] * inv;
}

// ---------------- wsum fp32 (fallback) ----------------
__global__ __launch_bounds__(256) void wsum_kernel(const float* __restrict__ x,
                                                   const float* __restrict__ w,
                                                   float* __restrict__ part) {
    int sc = blockIdx.x, b = blockIdx.y;
    int d0 = threadIdx.x * 4;
    const float* xb = x + ((size_t)b * NS + sc * 128) * ND;
    const float* wb = w + b * NS + sc * 128;
    float4 acc = {0.f, 0.f, 0.f, 0.f};
    for (int ss = 0; ss < 128; ++ss) {
        float wv = wb[ss];
        float4 xv = *(const float4*)&xb[(size_t)ss * ND + d0];
        acc.x += wv * xv.x;
        acc.y += wv * xv.y;
        acc.z += wv * xv.z;
        acc.w += wv * xv.w;
    }
    *(float4*)&part[(size_t)(b * 32 + sc) * ND + d0] = acc;
}

// ---------------- wsum bf16 (fast) ----------------
__global__ __launch_bounds__(256) void wsum_bf_kernel(const ushort* __restrict__ xbf,
                                                      const float* __restrict__ w,
                                                      float* __restrict__ part) {
    int sc = blockIdx.x, b = blockIdx.y;
    int d0 = threadIdx.x * 4;
    const ushort* xb = xbf + ((size_t)b * NS + sc * 128) * ND;
    const float* wb = w + b * NS + sc * 128;
    float4 acc = {0.f, 0.f, 0.f, 0.f};
    for (int ss = 0; ss < 128; ++ss) {
        float wv = wb[ss];
        ushort4 xv = *(const ushort4*)&xb[(size_t)ss * ND + d0];
        acc.x += wv * bf2f(xv.x);
        acc.y += wv * bf2f(xv.y);
        acc.z += wv * bf2f(xv.z);
        acc.w += wv * bf2f(xv.w);
    }
    *(float4*)&part[(size_t)(b * 32 + sc) * ND + d0] = acc;
}

// ---------------- reduce partials -> out ----------------
__global__ __launch_bounds__(256) void reduce_kernel(const float* __restrict__ part,
                                                     float* __restrict__ out) {
    int b = blockIdx.x;
    int d0 = threadIdx.x * 4;
    float4 acc = {0.f, 0.f, 0.f, 0.f};
#pragma unroll
    for (int sc = 0; sc < 32; ++sc) {
        float4 v = *(const float4*)&part[(size_t)(b * 32 + sc) * ND + d0];
        acc.x += v.x;
        acc.y += v.y;
        acc.z += v.z;
        acc.w += v.w;
    }
    *(float4*)&out[b * ND + d0] = acc;
}

extern "C" void kernel_launch(void* const* d_in, const int* in_sizes, int n_in,
                              void* d_out, int out_size, void* d_ws, size_t ws_size,
                              hipStream_t stream) {
    const float* x       = (const float*)d_in[0];
    const float* context = (const float*)d_in[1];
    const float* W_in    = (const float*)d_in[2];
    const float* b_in    = (const float*)d_in[3];
    const float* W_ctx   = (const float*)d_in[4];
    const float* b_ctx   = (const float*)d_in[5];
    const float* w_att   = (const float*)d_in[6];
    // b_att (d_in[7]): softmax is shift-invariant; it cancels.

    float* ws      = (float*)d_ws;
    float* t       = ws + WS_T;
    float* scores  = ws + WS_SCORES;
    float* weights = ws + WS_WEIGHTS;
    ushort* wbf16  = (ushort*)(ws + WS_SHARED);
    ushort* xbf16  = (ushort*)(ws + WS_XBF16);
    float* spart   = ws + WS_SPART;              // fast: spart, then part overlay
    float* partfb  = ws + WS_SHARED;             // fallback: part overlays wbf16
    float* out     = (float*)d_out;

    bool fast = ws_size >= WS_NEED;

    convw_kernel<<<dim3(512), 256, 0, stream>>>(W_in, wbf16);
    tvec_kernel<<<dim3(16, NB), 256, 0, stream>>>(context, W_ctx, b_in, b_ctx, t);
    if (fast) {
        convx_kernel<<<dim3(2048), 256, 0, stream>>>(x, xbf16);
        scores_tile_kernel<<<dim3(1024), 512, 0, stream>>>(xbf16, wbf16, t, w_att, spart);
        softmax4_kernel<<<dim3(NB), 256, 0, stream>>>(spart, weights);
        wsum_bf_kernel<<<dim3(32, NB), 256, 0, stream>>>(xbf16, weights, spart);
        reduce_kernel<<<dim3(NB), 256, 0, stream>>>(spart, out);
    } else {
        scores_mfma_kernel<<<dim3(NM / 64), 512, 0, stream>>>(x, wbf16, t, w_att, scores);
        softmax_kernel<<<dim3(NB), 256, 0, stream>>>(scores, weights);
        wsum_kernel<<<dim3(32, NB), 256, 0, stream>>>(x, weights, partfb);
        reduce_kernel<<<dim3(NB), 256, 0, stream>>>(partfb, out);
    }
}

// Round 12
// 287.238 us; speedup vs baseline: 1.0823x; 1.0520x over previous
//
#include <hip/hip_runtime.h>
#include <hip/hip_bf16.h>
#include <math.h>

#define NB 16
#define NS 4096
#define ND 1024
#define NM (NB * NS)

// workspace layout (float offsets)
#define WS_T       0                            // 16*1024
#define WS_SCORES  16384                        // 16*4096 (fallback path)
#define WS_WEIGHTS (WS_SCORES + NB * NS)        // 16*4096
#define WS_SHARED  (WS_WEIGHTS + NB * NS)       // 2MB: wbf16 (convw->scores); fallback: part overlay
#define WS_XBF16   (WS_SHARED + 524288)         // 67.1M ushorts (134 MB)
#define WS_SPART   (WS_XBF16 + 33554432)        // 2MB: spart (scores->softmax) then part (wsum->reduce)
#define WS_NEED    (((size_t)WS_SPART + 524288) * 4)

typedef short v8s __attribute__((ext_vector_type(8)));
typedef float v4f __attribute__((ext_vector_type(4)));
typedef unsigned short ushort;

#define G_AS __attribute__((address_space(1)))
#define L_AS __attribute__((address_space(3)))

__device__ __forceinline__ ushort f2bf(float f) {
    __hip_bfloat16 h = __float2bfloat16(f);
    return *reinterpret_cast<ushort*>(&h);
}

__device__ __forceinline__ float bf2f(ushort u) {
    return __uint_as_float(((unsigned)u) << 16);
}

__device__ __forceinline__ float fast_tanh(float x) {
    float e = __expf(2.0f * x);
    return 1.0f - 2.0f / (e + 1.0f);
}

// ---------------- kernel 0a: W_in fp32 -> bf16 ----------------
__global__ __launch_bounds__(256) void convw_kernel(const float* __restrict__ W,
                                                    ushort* __restrict__ Wb) {
    int flat = blockIdx.x * 256 + threadIdx.x;
#pragma unroll
    for (int j = 0; j < 2; ++j) {
        int idx = flat + j * 131072;
        float4 v = ((const float4*)W)[idx];
        ushort4 o;
        o.x = f2bf(v.x); o.y = f2bf(v.y); o.z = f2bf(v.z); o.w = f2bf(v.w);
        ((ushort4*)Wb)[idx] = o;
    }
}

// ---------------- kernel 0b: x fp32 -> bf16 (fast path only) ----------------
__global__ __launch_bounds__(256) void convx_kernel(const float* __restrict__ x,
                                                    ushort* __restrict__ xb) {
    size_t base = (size_t)blockIdx.x * 256 + threadIdx.x;   // grid 2048
#pragma unroll
    for (int i = 0; i < 16; ++i) {
        size_t idx8 = base + (size_t)i * 524288;
        float4 a = ((const float4*)x)[idx8 * 2];
        float4 c = ((const float4*)x)[idx8 * 2 + 1];
        v8s o;
        o[0] = (short)f2bf(a.x); o[1] = (short)f2bf(a.y);
        o[2] = (short)f2bf(a.z); o[3] = (short)f2bf(a.w);
        o[4] = (short)f2bf(c.x); o[5] = (short)f2bf(c.y);
        o[6] = (short)f2bf(c.z); o[7] = (short)f2bf(c.w);
        ((v8s*)xb)[idx8] = o;
    }
}

// ---------------- kernel 1: t[b][e] = b_in[e]+b_ctx[e]+context[b].W_ctx[e] ----------------
__global__ __launch_bounds__(256) void tvec_kernel(const float* __restrict__ context,
                                                   const float* __restrict__ W_ctx,
                                                   const float* __restrict__ b_in,
                                                   const float* __restrict__ b_ctx,
                                                   float* __restrict__ t) {
    __shared__ float ctx[ND];
    int b = blockIdx.y;
    int tid = threadIdx.x;
    for (int i = tid; i < ND; i += 256) ctx[i] = context[b * ND + i];
    __syncthreads();
    int e = blockIdx.x * 64 + (tid >> 2);
    int kq = tid & 3;
    const float4* wr = (const float4*)(W_ctx + (size_t)e * ND + kq * 256);
    const float4* cr = (const float4*)(ctx + kq * 256);
    float acc = 0.f;
#pragma unroll 4
    for (int k = 0; k < 64; ++k) {
        float4 w = wr[k];
        float4 c = cr[k];
        acc += c.x * w.x + c.y * w.y + c.z * w.z + c.w * w.w;
    }
    acc += __shfl_xor(acc, 1);
    acc += __shfl_xor(acc, 2);
    if (kq == 0) t[b * ND + e] = acc + b_in[e] + b_ctx[e];
}

// ================= FAST scores: 256x256xBK32, 8 waves, depth-3 counted-vmcnt pipeline =================
// Round-9 structure (best measured) with: 4 LDS buffers (128 KB), stage k+3, vmcnt(12) per
// step (waits only 3-step-old loads; in-order vmcnt retirement makes this exact), no setprio.
// 512 thr / 8 waves (2M x 4N), per-wave 128x64, acc[8][4]=128 AGPR, fragment-order LDS.
__global__ __launch_bounds__(512) void scores_tile_kernel(const ushort* __restrict__ xbf,
                                                          const ushort* __restrict__ Wb,
                                                          const float* __restrict__ t,
                                                          const float* __restrict__ w_att,
                                                          float* __restrict__ spart) {
    __shared__ ushort As[4][8192];   // 16 KB each: granule (row*4+kq)*8
    __shared__ ushort Bs[4][8192];
    __shared__ float red[8][128];

    int tid = threadIdx.x;
    int o = blockIdx.x;              // 1024 blocks = 8 xcd x (32 rt x 4 ct)
    int xcd = o & 7, idx = o >> 3;
    int ct = idx & 3;
    int rt = xcd * 32 + (idx >> 2);
    int row0 = rt << 8;
    int e0 = ct << 8;
    int b = row0 >> 12;              // 256 | 4096

    // staging: granule g = tid and tid+512; row/ecol = g>>2, kq = g&3
    const ushort* gaA0 = xbf + (size_t)(row0 + (tid >> 2)) * ND + (tid & 3) * 8;
    const ushort* gaA1 = gaA0 + (size_t)128 * ND;
    const ushort* gaB0 = Wb + (size_t)(e0 + (tid >> 2)) * ND + (tid & 3) * 8;
    const ushort* gaB1 = gaB0 + (size_t)128 * ND;

    int wid = tid >> 6, l = tid & 63;
    int l15 = l & 15, kq4 = l >> 4;
    int WM = (wid >> 2) * 128;       // wave M base
    int WN = (wid & 3) * 64;         // wave N base

    v4f acc[8][4];
#pragma unroll
    for (int i = 0; i < 8; ++i)
#pragma unroll
        for (int j = 0; j < 4; ++j) acc[i][j] = (v4f)(0.f);

#define STAGE(BUF, KO)                                                                                                 \
    {                                                                                                                  \
        __builtin_amdgcn_global_load_lds((const G_AS void*)(gaA0 + (KO)), (L_AS void*)&As[BUF][tid * 8], 16, 0, 0);    \
        __builtin_amdgcn_global_load_lds((const G_AS void*)(gaA1 + (KO)), (L_AS void*)&As[BUF][(tid + 512) * 8], 16, 0, 0); \
        __builtin_amdgcn_global_load_lds((const G_AS void*)(gaB0 + (KO)), (L_AS void*)&Bs[BUF][tid * 8], 16, 0, 0);    \
        __builtin_amdgcn_global_load_lds((const G_AS void*)(gaB1 + (KO)), (L_AS void*)&Bs[BUF][(tid + 512) * 8], 16, 0, 0); \
    }

#define COMPUTE(BUF)                                                                              \
    {                                                                                             \
        v8s bf[4];                                                                                \
        _Pragma("unroll") for (int nf = 0; nf < 4; ++nf)                                          \
            bf[nf] = *(const v8s*)&Bs[BUF][((WN + nf * 16 + l15) * 4 + kq4) * 8];                 \
        _Pragma("unroll") for (int g = 0; g < 2; ++g) {                                           \
            v8s af[4];                                                                            \
            _Pragma("unroll") for (int j = 0; j < 4; ++j)                                         \
                af[j] = *(const v8s*)&As[BUF][((WM + (g * 4 + j) * 16 + l15) * 4 + kq4) * 8];     \
            _Pragma("unroll") for (int j = 0; j < 4; ++j)                                         \
                _Pragma("unroll") for (int nf = 0; nf < 4; ++nf)                                  \
                    acc[g * 4 + j][nf] = __builtin_amdgcn_mfma_f32_16x16x32_bf16(                 \
                        af[j], bf[nf], acc[g * 4 + j][nf], 0, 0, 0);                              \
        }                                                                                         \
    }

#define KSTEP(KT, BUF, STBUF, VMTOK, DOST)                           \
    {                                                                \
        __builtin_amdgcn_s_barrier();                                \
        if (DOST) STAGE(STBUF, ((KT) + 3) * 32);                     \
        asm volatile("s_waitcnt vmcnt(" VMTOK ")" ::: "memory");     \
        __builtin_amdgcn_s_barrier();                                \
        asm volatile("" ::: "memory");                               \
        COMPUTE(BUF);                                                \
    }

    // prologue: tiles 0,1,2 in flight (12 load-insts outstanding per thread)
    STAGE(0, 0);
    STAGE(1, 32);
    STAGE(2, 64);
    asm volatile("s_waitcnt vmcnt(8)" ::: "memory");   // tile 0 landed
    __builtin_amdgcn_s_barrier();

    // main: steps 0..27 (7 x 4), each stages tile kt+3, waits only 3-step-old loads
    for (int tt = 0; tt < 7; ++tt) {
        KSTEP(4 * tt + 0, 0, 3, "12", true);
        KSTEP(4 * tt + 1, 1, 0, "12", true);
        KSTEP(4 * tt + 2, 2, 1, "12", true);
        KSTEP(4 * tt + 3, 3, 2, "12", true);
    }
    // step 28: stages tile 31 into buf3
    KSTEP(28, 0, 3, "12", true);
    // tail: steps 29,30,31 drain gradually
    KSTEP(29, 1, 0, "8", false);
    KSTEP(30, 2, 0, "4", false);
    KSTEP(31, 3, 0, "0", false);

#undef KSTEP
#undef COMPUTE
#undef STAGE

    // ---- fused epilogue: tanh + dot(w_att) over this wave's 64 e-cols ----
    float s[8][4];
#pragma unroll
    for (int i = 0; i < 8; ++i)
#pragma unroll
        for (int j = 0; j < 4; ++j) s[i][j] = 0.f;

#pragma unroll
    for (int nf = 0; nf < 4; ++nf) {
        int e = e0 + WN + nf * 16 + l15;
        float tv = t[b * ND + e];
        float wv = w_att[e];
#pragma unroll
        for (int mf = 0; mf < 8; ++mf)
#pragma unroll
            for (int r = 0; r < 4; ++r)
                s[mf][r] += fast_tanh(acc[mf][nf][r] + tv) * wv;
    }
#pragma unroll
    for (int mf = 0; mf < 8; ++mf)
#pragma unroll
        for (int r = 0; r < 4; ++r) {
            float v = s[mf][r];
            v += __shfl_xor(v, 1);
            v += __shfl_xor(v, 2);
            v += __shfl_xor(v, 4);
            v += __shfl_xor(v, 8);
            s[mf][r] = v;
        }
    if (l15 == 0) {
#pragma unroll
        for (int mf = 0; mf < 8; ++mf)
#pragma unroll
            for (int r = 0; r < 4; ++r)
                red[wid][mf * 16 + kq4 * 4 + r] = s[mf][r];
    }
    __syncthreads();
    if (tid < 256) {
        int mg = tid >> 7;
        int rl = tid & 127;
        float v = red[mg * 4 + 0][rl] + red[mg * 4 + 1][rl] +
                  red[mg * 4 + 2][rl] + red[mg * 4 + 3][rl];
        spart[ct * 65536 + row0 + mg * 128 + rl] = v;
    }
}

// ================= FALLBACK scores (round-3 verbatim, proven) =================
__global__ __launch_bounds__(512) void scores_mfma_kernel(const float* __restrict__ x,
                                                          const ushort* __restrict__ Wb,
                                                          const float* __restrict__ t,
                                                          const float* __restrict__ w_att,
                                                          float* __restrict__ scores) {
    __shared__ ushort As[2][64 * 256];
    __shared__ float red[8][64];

    int tid = threadIdx.x;
    int row0 = blockIdx.x * 64;
    int b = row0 >> 12;
    const float4* xf4 = (const float4*)x;

    int sr = tid >> 3;
    int sc = tid & 7;
    int swzbase = (sr & 7) << 3;

    float4 nx[8];
#pragma unroll
    for (int j = 0; j < 8; ++j)
        nx[j] = xf4[(size_t)(row0 + sr) * 256 + sc + j * 8];
#pragma unroll
    for (int j = 0; j < 8; ++j) {
        int c4 = sc + j * 8;
        ushort4 o;
        o.x = f2bf(nx[j].x); o.y = f2bf(nx[j].y); o.z = f2bf(nx[j].z); o.w = f2bf(nx[j].w);
        *(ushort4*)&As[0][sr * 256 + ((c4 * 4) ^ swzbase)] = o;
    }
    __syncthreads();

    int w = tid >> 6;
    int l = tid & 63;
    int l15 = l & 15;
    int kofs = (l >> 4) * 8;
    int xorv = (l & 7) << 3;
    int n0 = w * 128;

    v4f acc[2][4][4];
#pragma unroll
    for (int p = 0; p < 2; ++p)
#pragma unroll
        for (int i = 0; i < 4; ++i)
#pragma unroll
            for (int j = 0; j < 4; ++j) acc[p][i][j] = (v4f)(0.f);

    const ushort* bbase0 = Wb + (size_t)(n0 + l15) * ND + kofs;
    const ushort* bbase1 = bbase0 + (size_t)64 * ND;

#pragma unroll
    for (int kh = 0; kh < 4; ++kh) {
        if (kh < 3) {
#pragma unroll
            for (int j = 0; j < 8; ++j)
                nx[j] = xf4[(size_t)(row0 + sr) * 256 + (kh + 1) * 64 + sc + j * 8];
        }
        const ushort* Ab = &As[kh & 1][0];
        int kb = kh * 256;

        v8s b0c[4], b0n[4], b1[4];
#pragma unroll
        for (int nf = 0; nf < 4; ++nf) b0c[nf] = *(const v8s*)(bbase0 + (size_t)nf * 16 * ND + kb);

#pragma unroll
        for (int ks = 0; ks < 8; ++ks) {
            int kk = kb + ks * 32;
            int elem = (ks * 32 + kofs) ^ xorv;
            v8s af[4];
#pragma unroll
            for (int mf = 0; mf < 4; ++mf)
                af[mf] = *(const v8s*)&Ab[(mf * 16 + l15) * 256 + elem];
#pragma unroll
            for (int nf = 0; nf < 4; ++nf)
                b1[nf] = *(const v8s*)(bbase1 + (size_t)nf * 16 * ND + kk);
            if (ks < 7) {
#pragma unroll
                for (int nf = 0; nf < 4; ++nf)
                    b0n[nf] = *(const v8s*)(bbase0 + (size_t)nf * 16 * ND + kk + 32);
            }
#pragma unroll
            for (int mf = 0; mf < 4; ++mf)
#pragma unroll
                for (int nf = 0; nf < 4; ++nf)
                    acc[0][mf][nf] = __builtin_amdgcn_mfma_f32_16x16x32_bf16(
                        af[mf], b0c[nf], acc[0][mf][nf], 0, 0, 0);
#pragma unroll
            for (int mf = 0; mf < 4; ++mf)
#pragma unroll
                for (int nf = 0; nf < 4; ++nf)
                    acc[1][mf][nf] = __builtin_amdgcn_mfma_f32_16x16x32_bf16(
                        af[mf], b1[nf], acc[1][mf][nf], 0, 0, 0);
#pragma unroll
            for (int nf = 0; nf < 4; ++nf) b0c[nf] = b0n[nf];
        }

        if (kh < 3) {
#pragma unroll
            for (int j = 0; j < 8; ++j) {
                int c4 = sc + j * 8;
                ushort4 o;
                o.x = f2bf(nx[j].x); o.y = f2bf(nx[j].y); o.z = f2bf(nx[j].z); o.w = f2bf(nx[j].w);
                *(ushort4*)&As[(kh + 1) & 1][sr * 256 + ((c4 * 4) ^ swzbase)] = o;
            }
            __syncthreads();
        }
    }

    float s[4][4];
#pragma unroll
    for (int i = 0; i < 4; ++i)
#pragma unroll
        for (int j = 0; j < 4; ++j) s[i][j] = 0.f;

#pragma unroll
    for (int pass = 0; pass < 2; ++pass)
#pragma unroll
        for (int nf = 0; nf < 4; ++nf) {
            int e = n0 + pass * 64 + nf * 16 + l15;
            float tv = t[b * ND + e];
            float wv = w_att[e];
#pragma unroll
            for (int mf = 0; mf < 4; ++mf)
#pragma unroll
                for (int r = 0; r < 4; ++r)
                    s[mf][r] += fast_tanh(acc[pass][mf][nf][r] + tv) * wv;
        }

#pragma unroll
    for (int mf = 0; mf < 4; ++mf)
#pragma unroll
        for (int r = 0; r < 4; ++r) {
            float v = s[mf][r];
            v += __shfl_xor(v, 1);
            v += __shfl_xor(v, 2);
            v += __shfl_xor(v, 4);
            v += __shfl_xor(v, 8);
            s[mf][r] = v;
        }
    if (l15 == 0) {
#pragma unroll
        for (int mf = 0; mf < 4; ++mf)
#pragma unroll
            for (int r = 0; r < 4; ++r)
                red[w][mf * 16 + (l >> 4) * 4 + r] = s[mf][r];
    }
    __syncthreads();
    if (tid < 64) {
        float v = 0.f;
#pragma unroll
        for (int ww = 0; ww < 8; ++ww) v += red[ww][tid];
        scores[(size_t)b * NS + (row0 & (NS - 1)) + tid] = v;
    }
}

// ---------------- softmax (fast): sum 4 col-tile partials, then softmax ----------------
__global__ __launch_bounds__(256) void softmax4_kernel(const float* __restrict__ spart,
                                                       float* __restrict__ weights) {
    int b = blockIdx.x;
    int tid = threadIdx.x;
    float v[16];
    float lmax = -1e30f;
#pragma unroll
    for (int i = 0; i < 16; ++i) {
        int grow = b * NS + tid + i * 256;
        float sum = 0.f;
#pragma unroll
        for (int c = 0; c < 4; ++c) sum += spart[c * 65536 + grow];
        v[i] = sum;
        lmax = fmaxf(lmax, sum);
    }
#pragma unroll
    for (int off = 32; off >= 1; off >>= 1) lmax = fmaxf(lmax, __shfl_xor(lmax, off));
    __shared__ float redm[4];
    int wave = tid >> 6;
    if ((tid & 63) == 0) redm[wave] = lmax;
    __syncthreads();
    float bmax = fmaxf(fmaxf(redm[0], redm[1]), fmaxf(redm[2], redm[3]));

    float lsum = 0.f;
#pragma unroll
    for (int i = 0; i < 16; ++i) {
        v[i] = expf(v[i] - bmax);
        lsum += v[i];
    }
#pragma unroll
    for (int off = 32; off >= 1; off >>= 1) lsum += __shfl_xor(lsum, off);
    __shared__ float reds[4];
    if ((tid & 63) == 0) reds[wave] = lsum;
    __syncthreads();
    float inv = 1.0f / (reds[0] + reds[1] + reds[2] + reds[3]);
#pragma unroll
    for (int i = 0; i < 16; ++i) weights[b * NS + tid + i * 256] = v[i] * inv;
}

// ---------------- softmax (fallback): plain ----------------
__global__ __launch_bounds__(256) void softmax_kernel(const float* __restrict__ scores,
                                                      float* __restrict__ weights) {
    int b = blockIdx.x;
    int tid = threadIdx.x;
    float v[16];
    float lmax = -1e30f;
#pragma unroll
    for (int i = 0; i < 16; ++i) {
        v[i] = scores[b * NS + tid + i * 256];
        lmax = fmaxf(lmax, v[i]);
    }
#pragma unroll
    for (int off = 32; off >= 1; off >>= 1) lmax = fmaxf(lmax, __shfl_xor(lmax, off));
    __shared__ float redm[4];
    int wave = tid >> 6;
    if ((tid & 63) == 0) redm[wave] = lmax;
    __syncthreads();
    float bmax = fmaxf(fmaxf(redm[0], redm[1]), fmaxf(redm[2], redm[3]));

    float lsum = 0.f;
#pragma unroll
    for (int i = 0; i < 16; ++i) {
        v[i] = expf(v[i] - bmax);
        lsum += v[i];
    }
#pragma unroll
    for (int off = 32; off >= 1; off >>= 1) lsum += __shfl_xor(lsum, off);
    __shared__ float reds[4];
    if ((tid & 63) == 0) reds[wave] = lsum;
    __syncthreads();
    float inv = 1.0f / (reds[0] + reds[1] + reds[2] + reds[3]);
#pragma unroll
    for (int i = 0; i < 16; ++i) weights[b * NS + tid + i * 256] = v[i] * inv;
}

// ---------------- wsum fp32 (fallback) ----------------
__global__ __launch_bounds__(256) void wsum_kernel(const float* __restrict__ x,
                                                   const float* __restrict__ w,
                                                   float* __restrict__ part) {
    int sc = blockIdx.x, b = blockIdx.y;
    int d0 = threadIdx.x * 4;
    const float* xb = x + ((size_t)b * NS + sc * 128) * ND;
    const float* wb = w + b * NS + sc * 128;
    float4 acc = {0.f, 0.f, 0.f, 0.f};
    for (int ss = 0; ss < 128; ++ss) {
        float wv = wb[ss];
        float4 xv = *(const float4*)&xb[(size_t)ss * ND + d0];
        acc.x += wv * xv.x;
        acc.y += wv * xv.y;
        acc.z += wv * xv.z;
        acc.w += wv * xv.w;
    }
    *(float4*)&part[(size_t)(b * 32 + sc) * ND + d0] = acc;
}

// ---------------- wsum bf16 (fast) ----------------
__global__ __launch_bounds__(256) void wsum_bf_kernel(const ushort* __restrict__ xbf,
                                                      const float* __restrict__ w,
                                                      float* __restrict__ part) {
    int sc = blockIdx.x, b = blockIdx.y;
    int d0 = threadIdx.x * 4;
    const ushort* xb = xbf + ((size_t)b * NS + sc * 128) * ND;
    const float* wb = w + b * NS + sc * 128;
    float4 acc = {0.f, 0.f, 0.f, 0.f};
    for (int ss = 0; ss < 128; ++ss) {
        float wv = wb[ss];
        ushort4 xv = *(const ushort4*)&xb[(size_t)ss * ND + d0];
        acc.x += wv * bf2f(xv.x);
        acc.y += wv * bf2f(xv.y);
        acc.z += wv * bf2f(xv.z);
        acc.w += wv * bf2f(xv.w);
    }
    *(float4*)&part[(size_t)(b * 32 + sc) * ND + d0] = acc;
}

// ---------------- reduce partials -> out ----------------
__global__ __launch_bounds__(256) void reduce_kernel(const float* __restrict__ part,
                                                     float* __restrict__ out) {
    int b = blockIdx.x;
    int d0 = threadIdx.x * 4;
    float4 acc = {0.f, 0.f, 0.f, 0.f};
#pragma unroll
    for (int sc = 0; sc < 32; ++sc) {
        float4 v = *(const float4*)&part[(size_t)(b * 32 + sc) * ND + d0];
        acc.x += v.x;
        acc.y += v.y;
        acc.z += v.z;
        acc.w += v.w;
    }
    *(float4*)&out[b * ND + d0] = acc;
}

extern "C" void kernel_launch(void* const* d_in, const int* in_sizes, int n_in,
                              void* d_out, int out_size, void* d_ws, size_t ws_size,
                              hipStream_t stream) {
    const float* x       = (const float*)d_in[0];
    const float* context = (const float*)d_in[1];
    const float* W_in    = (const float*)d_in[2];
    const float* b_in    = (const float*)d_in[3];
    const float* W_ctx   = (const float*)d_in[4];
    const float* b_ctx   = (const float*)d_in[5];
    const float* w_att   = (const float*)d_in[6];
    // b_att (d_in[7]): softmax is shift-invariant; it cancels.

    float* ws      = (float*)d_ws;
    float* t       = ws + WS_T;
    float* scores  = ws + WS_SCORES;
    float* weights = ws + WS_WEIGHTS;
    ushort* wbf16  = (ushort*)(ws + WS_SHARED);
    ushort* xbf16  = (ushort*)(ws + WS_XBF16);
    float* spart   = ws + WS_SPART;              // fast: spart, then part overlay
    float* partfb  = ws + WS_SHARED;             // fallback: part overlays wbf16
    float* out     = (float*)d_out;

    bool fast = ws_size >= WS_NEED;

    convw_kernel<<<dim3(512), 256, 0, stream>>>(W_in, wbf16);
    tvec_kernel<<<dim3(16, NB), 256, 0, stream>>>(context, W_ctx, b_in, b_ctx, t);
    if (fast) {
        convx_kernel<<<dim3(2048), 256, 0, stream>>>(x, xbf16);
        scores_tile_kernel<<<dim3(1024), 512, 0, stream>>>(xbf16, wbf16, t, w_att, spart);
        softmax4_kernel<<<dim3(NB), 256, 0, stream>>>(spart, weights);
        wsum_bf_kernel<<<dim3(32, NB), 256, 0, stream>>>(xbf16, weights, spart);
        reduce_kernel<<<dim3(NB), 256, 0, stream>>>(spart, out);
    } else {
        scores_mfma_kernel<<<dim3(NM / 64), 512, 0, stream>>>(x, wbf16, t, w_att, scores);
        softmax_kernel<<<dim3(NB), 256, 0, stream>>>(scores, weights);
        wsum_kernel<<<dim3(32, NB), 256, 0, stream>>>(x, weights, partfb);
        reduce_kernel<<<dim3(NB), 256, 0, stream>>>(partfb, out);
    }
}